// Round 8
// baseline (387.336 us; speedup 1.0000x reference)
//
#include <hip/hip_runtime.h>

typedef unsigned int u32;
typedef unsigned short u16;
typedef unsigned long long u64;

// Problem constants
#define NPTS 65536
#define PCLD 2048
#define KNN 20
#define HD 128
#define HD2 256
// activations at rest: ROW-MAJOR order-encoded u16: he[row][128] (256 B/row),
// stored in MORTON-SORTED order per cloud so the fused gather's neighbor
// rows are spatially local -> L1-resident.

typedef __attribute__((ext_vector_type(8))) short bf16x8;   // 8 bf16 (4 VGPRs)
typedef __attribute__((ext_vector_type(4))) float f32x4;    // C/D frag
typedef unsigned short us2 __attribute__((ext_vector_type(2)));

__device__ __forceinline__ u16 f2bf(float f) {
    u32 u = __float_as_uint(f);
    u32 r = (u + 0x7FFFu + ((u >> 16) & 1u)) >> 16;  // RNE
    return (u16)r;
}
// order-encode: bf16 bits -> monotone u16 (unsigned compare == float compare)
__device__ __forceinline__ u32 enc2(u32 b) {             // 2 packed values
    u32 s = (b >> 15) & 0x00010001u;
    return b ^ (s * 0x7FFFu) ^ 0x80008000u;
}
__device__ __forceinline__ u32 dec2(u32 e) {
    u32 s = ((~e) >> 15) & 0x00010001u;
    return e ^ (s * 0x7FFFu) ^ 0x80008000u;
}
__device__ __forceinline__ u32 max2(u32 a, u32 b) {      // per-u16 unsigned max
#if __has_builtin(__builtin_elementwise_max)
    us2 x, y; __builtin_memcpy(&x, &a, 4); __builtin_memcpy(&y, &b, 4);
    us2 r = __builtin_elementwise_max(x, y);
    u32 o; __builtin_memcpy(&o, &r, 4); return o;
#else
    u32 lo = ((a & 0xFFFFu) > (b & 0xFFFFu)) ? (a & 0xFFFFu) : (b & 0xFFFFu);
    u32 hi = ((a >> 16) > (b >> 16)) ? (a & 0xFFFF0000u) : (b & 0xFFFF0000u);
    return lo | hi;
#endif
}

__device__ __forceinline__ u32 spread3(u32 v) {   // 7-bit -> bits {0,3,..,18}
    v &= 0x3FF;
    v = (v | (v << 16)) & 0x030000FF;
    v = (v | (v << 8))  & 0x0300F00F;
    v = (v | (v << 4))  & 0x030C30C3;
    v = (v | (v << 2))  & 0x09249249;
    return v;
}

// ---------------------------------------------------------------------------
// Spatial sort: per cloud, Morton-order the 2048 points. Pure storage
// permutation (numerics unchanged). perm[s] = orig local idx at sorted pos s;
// iperm[orig] = sorted pos. Bitonic sort on 32-bit keys (morton<<11 | idx);
// idx tiebreak makes the permutation deterministic.
// ---------------------------------------------------------------------------
__global__ __launch_bounds__(256) void sort_kernel(const float* __restrict__ x,
                                                   u16* __restrict__ perm,
                                                   u16* __restrict__ iperm) {
    __shared__ u32 keys[PCLD];      // 8 KB
    __shared__ float red[256];
    const int cloud = blockIdx.x;
    const int tid = threadIdx.x;
    const float* xc = x + (u64)cloud * PCLD * 3;

    // per-cloud bbox (block reduce)
    float mn[3] = {1e30f, 1e30f, 1e30f}, mx[3] = {-1e30f, -1e30f, -1e30f};
    for (int m = 0; m < 8; ++m) {
        int t = tid + 256 * m;
        float a = xc[3 * t], b = xc[3 * t + 1], c = xc[3 * t + 2];
        mn[0] = fminf(mn[0], a); mx[0] = fmaxf(mx[0], a);
        mn[1] = fminf(mn[1], b); mx[1] = fmaxf(mx[1], b);
        mn[2] = fminf(mn[2], c); mx[2] = fmaxf(mx[2], c);
    }
    float bmn[3], sc[3];
    for (int d = 0; d < 3; ++d) {
        red[tid] = mn[d]; __syncthreads();
        for (int s = 128; s > 0; s >>= 1) { if (tid < s) red[tid] = fminf(red[tid], red[tid + s]); __syncthreads(); }
        bmn[d] = red[0]; __syncthreads();
        red[tid] = mx[d]; __syncthreads();
        for (int s = 128; s > 0; s >>= 1) { if (tid < s) red[tid] = fmaxf(red[tid], red[tid + s]); __syncthreads(); }
        float rng = red[0] - bmn[d];
        sc[d] = 127.0f / fmaxf(rng, 1e-6f);
        __syncthreads();
    }

    // keys
    for (int m = 0; m < 8; ++m) {
        int t = tid + 256 * m;
        float a = xc[3 * t], b = xc[3 * t + 1], c = xc[3 * t + 2];
        u32 qa = (u32)fminf(fmaxf((a - bmn[0]) * sc[0], 0.0f), 127.0f);
        u32 qb = (u32)fminf(fmaxf((b - bmn[1]) * sc[1], 0.0f), 127.0f);
        u32 qc = (u32)fminf(fmaxf((c - bmn[2]) * sc[2], 0.0f), 127.0f);
        u32 mort = spread3(qa) | (spread3(qb) << 1) | (spread3(qc) << 2);  // 21 bits
        keys[t] = (mort << 11) | (u32)t;
    }
    __syncthreads();

    // bitonic sort, 1024 compare-swaps per step, 4 per thread
    for (int k = 2; k <= PCLD; k <<= 1) {
        for (int j = k >> 1; j > 0; j >>= 1) {
            for (int m = 0; m < 4; ++m) {
                int i = tid + 256 * m;                       // 0..1023
                int idx = ((i & ~(j - 1)) << 1) | (i & (j - 1));
                int l = idx | j;
                bool asc = ((idx & k) == 0);
                u32 a = keys[idx], b = keys[l];
                bool sw = asc ? (a > b) : (a < b);
                if (sw) { keys[idx] = b; keys[l] = a; }
            }
            __syncthreads();
        }
    }

    for (int m = 0; m < 8; ++m) {
        int s = tid + 256 * m;
        u16 o = (u16)(keys[s] & 0x7FF);
        perm[cloud * PCLD + s] = o;
        iperm[cloud * PCLD + o] = (u16)s;
    }
}

// ---------------------------------------------------------------------------
// Weight prep: fp32 -> bf16 + transpose (exact R3 version).
// ---------------------------------------------------------------------------
__global__ __launch_bounds__(256) void prep_kernel(
    const float* __restrict__ W1_0, const float* __restrict__ W2_0,
    const float* __restrict__ W1_1, const float* __restrict__ W2_1,
    u16* __restrict__ W1_0T, u16* __restrict__ W2_0T,
    u16* __restrict__ W1_1T, u16* __restrict__ W2_1T) {
    int id = blockIdx.x * 256 + threadIdx.x;   // 4 * 32768 threads
    int m = id >> 15, e = id & 32767;
    if (m == 0)      { int n = e >> 7, k = e & 127; W1_0T[e] = f2bf(W1_0[k * 256 + n]); }
    else if (m == 1) { int n = e >> 8, k = e & 255; W2_0T[e] = f2bf(W2_0[k * 128 + n]); }
    else if (m == 2) { int n = e >> 7, k = e & 127; W1_1T[e] = f2bf(W1_1[k * 256 + n]); }
    else             { int n = e >> 8, k = e & 255; W2_1T[e] = f2bf(W2_1[k * 128 + n]); }
}

// ---------------------------------------------------------------------------
// kNN — scan core is the EXACT R2 structure (PERMANENTLY FROZEN; failed
// attacks: R10 split 214, R12 shared-thr 188, R14 scalar loads 237).
// Only the prologue (stage iperm 4 KB) and epilogue (write row + neighbor
// ids in SORTED space) changed — the hot loop is byte-identical.
// ---------------------------------------------------------------------------
__global__ __launch_bounds__(256) void knn_kernel(const float* __restrict__ x,
                                                  const u16* __restrict__ iperm,
                                                  u16* __restrict__ nbr) {
    __shared__ float4 pts[PCLD];
    __shared__ u16 ipermL[PCLD];   // 4 KB
    const int cloud = blockIdx.x >> 3;
    const int qi = ((blockIdx.x & 7) << 8) + threadIdx.x;   // local query idx
    const float* xc = x + (u64)cloud * PCLD * 3;
    for (int t = threadIdx.x; t < PCLD; t += 256) {
        float a = xc[3 * t], b = xc[3 * t + 1], c = xc[3 * t + 2];
        float sq = __fadd_rn(__fadd_rn(__fmul_rn(a, a), __fmul_rn(b, b)), __fmul_rn(c, c));
        pts[t] = make_float4(a, b, c, sq);
        ipermL[t] = iperm[cloud * PCLD + t];
    }
    __syncthreads();
    const float4 q = pts[qi];
    const float qx = q.x, qy = q.y, qz = q.z, qs = q.w;
    const int lane = threadIdx.x & 63;
    u64 list[KNN];
#pragma unroll
    for (int k = 0; k < KNN; ++k) list[k] = 0xFF800000FFFFFFFFull;  // enc(+inf)
    float thr = __builtin_inff();

    for (int base = 0; base < PCLD; base += 64) {
        float4 cp = pts[base + lane];   // 1 ds_read_b128 per 64 candidates
        u64 mask = 0;
#pragma unroll
        for (int c = 0; c < 64; ++c) {
            float cx = __uint_as_float(__builtin_amdgcn_readlane(__float_as_uint(cp.x), c));
            float cy = __uint_as_float(__builtin_amdgcn_readlane(__float_as_uint(cp.y), c));
            float cz = __uint_as_float(__builtin_amdgcn_readlane(__float_as_uint(cp.z), c));
            float cs = __uint_as_float(__builtin_amdgcn_readlane(__float_as_uint(cp.w), c));
            float dot = __builtin_fmaf(cz, qz, __builtin_fmaf(cy, qy, __fmul_rn(cx, qx)));
            float d = __fsub_rn(__fadd_rn(qs, cs), __fmul_rn(2.0f, dot));
            if (d < thr) mask |= (1ull << c);
        }
        while (mask) {
            int c = __builtin_ctzll(mask);
            mask &= mask - 1;
            float4 p2 = pts[base + c];
            float dot = __builtin_fmaf(p2.z, qz, __builtin_fmaf(p2.y, qy, __fmul_rn(p2.x, qx)));
            float d = __fsub_rn(__fadd_rn(qs, p2.w), __fmul_rn(2.0f, dot));
            if (d < thr) {
                u32 ub = __float_as_uint(d);
                u32 e = (ub & 0x80000000u) ? ~ub : (ub | 0x80000000u);
                u64 key = (((u64)e) << 32) | (u32)(base + c);
#pragma unroll
                for (int k = 0; k < KNN; ++k) {
                    u64 lo = key < list[k] ? key : list[k];
                    u64 hi = key < list[k] ? list[k] : key;
                    list[k] = lo; key = hi;
                }
                u32 e19 = (u32)(list[KNN - 1] >> 32);
                u32 ud = (e19 & 0x80000000u) ? (e19 & 0x7FFFFFFFu) : ~e19;
                thr = __uint_as_float(ud);
            }
        }
    }
    // epilogue: write in SORTED space (row and neighbor ids)
    u16* out = nbr + ((u64)cloud * PCLD + ipermL[qi]) * KNN;
#pragma unroll
    for (int k = 0; k < KNN; ++k) out[k] = ipermL[(u32)list[k] & (PCLD - 1)];
}

// ---------------------------------------------------------------------------
// Transfer MLP: h0 = encode(bf16(x @ Wt + bt)), row-major he[row][128],
// written at the SORTED position (256-B row scatter).
// ---------------------------------------------------------------------------
__global__ __launch_bounds__(256) void feat_kernel(const float* __restrict__ x,
                                                   const float* __restrict__ Wt,
                                                   const float* __restrict__ bt,
                                                   const u16* __restrict__ iperm,
                                                   u16* __restrict__ h0e) {
    int gid = blockIdx.x * 256 + threadIdx.x;   // NPTS*16
    int i = gid >> 4;
    int g = gid & 15;            // 8-channel group within the row
    int c0 = g << 3;
    float x0 = x[3 * i], x1 = x[3 * i + 1], x2 = x[3 * i + 2];
    u32 o[4];
#pragma unroll
    for (int j = 0; j < 8; j += 2) {
        int c = c0 + j;
        float a0 = bt[c]     + x0 * Wt[c]     + x1 * Wt[128 + c]     + x2 * Wt[256 + c];
        float a1 = bt[c + 1] + x0 * Wt[c + 1] + x1 * Wt[128 + c + 1] + x2 * Wt[256 + c + 1];
        o[j >> 1] = enc2(((u32)f2bf(a0)) | (((u32)f2bf(a1)) << 16));
    }
    const int cl = i >> 11;
    const int ri = cl * PCLD + (int)iperm[i];   // sorted row
    uint4* dst = (uint4*)&h0e[(u64)ri * HD + c0];
    *dst = make_uint4(o[0], o[1], o[2], o[3]);
}

// ---------------------------------------------------------------------------
// Fused GEMM layer — R7 structure (coalesced quarters), operating in
// SORTED space: a 64-row tile is a spatial ball, its ~20-NN gather rows
// concentrate in ~150-250 distinct rows (~40-60 KB) -> L1-resident across
// the block's gather instructions (attacks the ~25 us/layer L1-miss cost
// R7 exposed). gemm1 epilogue un-permutes to original row order.
// ---------------------------------------------------------------------------
template <int RELU_OUT, int OUT_F32>
__global__ __launch_bounds__(256) void gemm_kernel(
    const u16* __restrict__ he, const u16* __restrict__ nbr_,
    const u16* __restrict__ perm_,
    const u16* __restrict__ W1T, const float* __restrict__ b1,
    const u16* __restrict__ W2T, const float* __restrict__ b2,
    const float* __restrict__ g, const float* __restrict__ be,
    const float* __restrict__ rm, const float* __restrict__ rv,
    void* __restrict__ hout_v) {
    __shared__ u16 aggL[64][136];   // +8 pad (272 B row stride = 17x16 B)
    __shared__ u16 hidL[64][264];   // +8 pad
    const int tid = threadIdx.x;
    // XCD-aware swizzle: 1024 blocks = 32 clouds x 32 tiles; b%8 == XCD id.
    const int b = blockIdx.x;
    const int xcd = b & 7, j = b >> 3;           // j in [0,128)
    const int cloud = xcd + 8 * (j >> 5);        // 4 clouds per XCD
    const int tile = j & 31;
    const int R = cloud * PCLD + tile * 64;      // global sorted row base

    // ---- Phase A: fused neighbor-max gather (L1/L2) + decode -> aggL
    {
        const int r = tid >> 2, cg = tid & 3;    // 64 rows x 4 thr
        const int co = cg * 8;                   // u16 offset of 16-B quarter
        const int grow = R + r;
        const u16* __restrict__ hrow = he + (u64)grow * HD;
        uint4 m0 = *(const uint4*)&hrow[co];
        uint4 m1 = *(const uint4*)&hrow[32 + co];
        uint4 m2 = *(const uint4*)&hrow[64 + co];
        uint4 m3 = *(const uint4*)&hrow[96 + co];
        const u64* nb8 = (const u64*)(nbr_ + (u64)grow * KNN);
        u64 nq[5];
#pragma unroll
        for (int w = 0; w < 5; ++w) nq[w] = nb8[w];
        const u16* __restrict__ hcl = he + (u64)cloud * PCLD * HD;
#pragma unroll 4
        for (int t = 0; t < KNN; ++t) {
            int loc = (int)(nq[t >> 2] >> ((t & 3) * 16)) & (PCLD - 1);
            const u16* __restrict__ vrow = hcl + (u64)loc * HD;
            uint4 v0 = *(const uint4*)&vrow[co];
            uint4 v1 = *(const uint4*)&vrow[32 + co];
            uint4 v2 = *(const uint4*)&vrow[64 + co];
            uint4 v3 = *(const uint4*)&vrow[96 + co];
            m0.x = max2(m0.x, v0.x); m0.y = max2(m0.y, v0.y);
            m0.z = max2(m0.z, v0.z); m0.w = max2(m0.w, v0.w);
            m1.x = max2(m1.x, v1.x); m1.y = max2(m1.y, v1.y);
            m1.z = max2(m1.z, v1.z); m1.w = max2(m1.w, v1.w);
            m2.x = max2(m2.x, v2.x); m2.y = max2(m2.y, v2.y);
            m2.z = max2(m2.z, v2.z); m2.w = max2(m2.w, v2.w);
            m3.x = max2(m3.x, v3.x); m3.y = max2(m3.y, v3.y);
            m3.z = max2(m3.z, v3.z); m3.w = max2(m3.w, v3.w);
        }
        *(uint4*)&aggL[r][co]      = make_uint4(dec2(m0.x), dec2(m0.y), dec2(m0.z), dec2(m0.w));
        *(uint4*)&aggL[r][32 + co] = make_uint4(dec2(m1.x), dec2(m1.y), dec2(m1.z), dec2(m1.w));
        *(uint4*)&aggL[r][64 + co] = make_uint4(dec2(m2.x), dec2(m2.y), dec2(m2.z), dec2(m2.w));
        *(uint4*)&aggL[r][96 + co] = make_uint4(dec2(m3.x), dec2(m3.y), dec2(m3.z), dec2(m3.w));
    }
    __syncthreads();

    const int wv = tid >> 6, lane = tid & 63;
    const int lr = lane & 15;
    const int lq = lane >> 4;

    // ---- Phase B: hid = relu(agg @ W1 + b1) -> hidL  (wave owns 64 n-cols)
    {
        f32x4 acc[4][4];
#pragma unroll
        for (int i = 0; i < 4; ++i)
#pragma unroll
            for (int j2 = 0; j2 < 4; ++j2) acc[i][j2] = (f32x4)(0.0f);
        const int nb0 = wv * 64;
#pragma unroll
        for (int ks = 0; ks < 4; ++ks) {
            const int kcol = ks * 32 + lq * 8;
            bf16x8 af[4], bfr[4];
#pragma unroll
            for (int mt = 0; mt < 4; ++mt)
                af[mt] = *(const bf16x8*)&aggL[mt * 16 + lr][kcol];
#pragma unroll
            for (int nt = 0; nt < 4; ++nt)
                bfr[nt] = *(const bf16x8*)&W1T[(u64)(nb0 + nt * 16 + lr) * HD + kcol];
#pragma unroll
            for (int mt = 0; mt < 4; ++mt)
#pragma unroll
                for (int nt = 0; nt < 4; ++nt)
                    acc[mt][nt] = __builtin_amdgcn_mfma_f32_16x16x32_bf16(af[mt], bfr[nt], acc[mt][nt], 0, 0, 0);
        }
#pragma unroll
        for (int nt = 0; nt < 4; ++nt) {
            const int c = nb0 + nt * 16 + lr;
            const float bias = b1[c];
#pragma unroll
            for (int mt = 0; mt < 4; ++mt)
#pragma unroll
                for (int r2 = 0; r2 < 4; ++r2) {
                    float v = fmaxf(acc[mt][nt][r2] + bias, 0.0f);
                    hidL[mt * 16 + lq * 4 + r2][c] = f2bf(v);
                }
        }
    }
    __syncthreads();

    // ---- Phase C: out = BN(hid @ W2 + b2) (+ReLU) -> global
    {
        f32x4 acc[4][2];
#pragma unroll
        for (int i = 0; i < 4; ++i) { acc[i][0] = (f32x4)(0.0f); acc[i][1] = (f32x4)(0.0f); }
        const int nb0 = wv * 32;
#pragma unroll
        for (int ks = 0; ks < 8; ++ks) {
            const int kcol = ks * 32 + lq * 8;
            bf16x8 af[4], bfr[2];
#pragma unroll
            for (int mt = 0; mt < 4; ++mt)
                af[mt] = *(const bf16x8*)&hidL[mt * 16 + lr][kcol];
#pragma unroll
            for (int nt = 0; nt < 2; ++nt)
                bfr[nt] = *(const bf16x8*)&W2T[(u64)(nb0 + nt * 16 + lr) * HD2 + kcol];
#pragma unroll
            for (int mt = 0; mt < 4; ++mt)
#pragma unroll
                for (int nt = 0; nt < 2; ++nt)
                    acc[mt][nt] = __builtin_amdgcn_mfma_f32_16x16x32_bf16(af[mt], bfr[nt], acc[mt][nt], 0, 0, 0);
        }
#pragma unroll
        for (int nt = 0; nt < 2; ++nt) {
            const int c = nb0 + nt * 16 + lr;
            const float bias = b2[c];
            const float sc = g[c] * (1.0f / sqrtf(rv[c] + 1e-5f));
            const float rmc = rm[c];
            const float bec = be[c];
#pragma unroll
            for (int mt = 0; mt < 4; ++mt)
#pragma unroll
                for (int r2 = 0; r2 < 4; ++r2) {
                    float v = acc[mt][nt][r2] + bias;
                    v = (v - rmc) * sc + bec;
                    if (RELU_OUT) v = fmaxf(v, 0.0f);
                    const int lrow = tile * 64 + mt * 16 + lq * 4 + r2;   // local sorted
                    if (OUT_F32) {
                        const int orow = cloud * PCLD + (int)perm_[cloud * PCLD + lrow];
                        ((float*)hout_v)[(u64)orow * HD + c] = v;   // un-permute
                    } else {
                        u16 bb = f2bf(v);
                        u16 e = bb ^ ((bb & 0x8000u) ? (u16)0xFFFFu : (u16)0x8000u);
                        ((u16*)hout_v)[(u64)(cloud * PCLD + lrow) * HD + c] = e;  // stay sorted
                    }
                }
        }
    }
}

// ---------------------------------------------------------------------------
extern "C" void kernel_launch(void* const* d_in, const int* in_sizes, int n_in,
                              void* d_out, int out_size, void* d_ws, size_t ws_size,
                              hipStream_t stream) {
    const float* x    = (const float*)d_in[0];
    const float* Wt   = (const float*)d_in[2];
    const float* bt   = (const float*)d_in[3];
    const float* W1_0 = (const float*)d_in[4];
    const float* b1_0 = (const float*)d_in[5];
    const float* W2_0 = (const float*)d_in[6];
    const float* b2_0 = (const float*)d_in[7];
    const float* g0   = (const float*)d_in[8];
    const float* be0  = (const float*)d_in[9];
    const float* rm0  = (const float*)d_in[10];
    const float* rv0  = (const float*)d_in[11];
    const float* W1_1 = (const float*)d_in[12];
    const float* b1_1 = (const float*)d_in[13];
    const float* W2_1 = (const float*)d_in[14];
    const float* b2_1 = (const float*)d_in[15];
    const float* g1   = (const float*)d_in[16];
    const float* be1  = (const float*)d_in[17];
    const float* rm1  = (const float*)d_in[18];
    const float* rv1  = (const float*)d_in[19];

    char* ws = (char*)d_ws;
    u16* he0  = (u16*)ws;                                   // 16 MB layer-0 acts (sorted)
    u16* he1  = (u16*)(ws + 16777216);                      // 16 MB layer-1 acts (sorted)
    u16* W10T = (u16*)(ws + 2 * 16777216);                  // 64 KB each
    u16* W20T = W10T + 32768;
    u16* W11T = W20T + 32768;
    u16* W21T = W11T + 32768;
    u16* nbr  = (u16*)(ws + 2 * 16777216 + 4 * 65536);      // 2.62 MB (sorted space)
    u16* perm = nbr + (u64)NPTS * KNN;                      // 128 KB
    u16* iperm = perm + NPTS;                               // 128 KB
    // total ws ~36.7 MB

    sort_kernel<<<32, 256, 0, stream>>>(x, perm, iperm);
    knn_kernel<<<256, 256, 0, stream>>>(x, iperm, nbr);
    prep_kernel<<<512, 256, 0, stream>>>(W1_0, W2_0, W1_1, W2_1, W10T, W20T, W11T, W21T);
    feat_kernel<<<4096, 256, 0, stream>>>(x, Wt, bt, iperm, he0);
    // layer 0: fused gather+GEMM, he0 -> he1 (sorted space)
    gemm_kernel<1, 0><<<1024, 256, 0, stream>>>(he0, nbr, perm, W10T, b1_0, W20T, b2_0,
                                                g0, be0, rm0, rv0, he1);
    // layer 1: fused gather+GEMM, he1 -> d_out (fp32, un-permuted)
    gemm_kernel<0, 1><<<1024, 256, 0, stream>>>(he1, nbr, perm, W11T, b1_1, W21T, b2_1,
                                                g1, be1, rm1, rv1, d_out);
}

// Round 9
// 360.117 us; speedup vs baseline: 1.0756x; 1.0756x over previous
//
#include <hip/hip_runtime.h>

typedef unsigned int u32;
typedef unsigned short u16;
typedef unsigned long long u64;

// Problem constants
#define NPTS 65536
#define PCLD 2048
#define KNN 20
#define HD 128
#define HD2 256
// activations at rest: ROW-MAJOR order-encoded u16: he[row][128] (256 B/row),
// stored in MORTON-SORTED order per cloud so the fused gather's neighbor
// rows are spatially local. knn stays in ORIGINAL space (frozen); a tiny
// remap kernel translates nbr to sorted space once.

typedef __attribute__((ext_vector_type(8))) short bf16x8;   // 8 bf16 (4 VGPRs)
typedef __attribute__((ext_vector_type(4))) float f32x4;    // C/D frag
typedef unsigned short us2 __attribute__((ext_vector_type(2)));

__device__ __forceinline__ u16 f2bf(float f) {
    u32 u = __float_as_uint(f);
    u32 r = (u + 0x7FFFu + ((u >> 16) & 1u)) >> 16;  // RNE
    return (u16)r;
}
// order-encode: bf16 bits -> monotone u16 (unsigned compare == float compare)
__device__ __forceinline__ u32 enc2(u32 b) {             // 2 packed values
    u32 s = (b >> 15) & 0x00010001u;
    return b ^ (s * 0x7FFFu) ^ 0x80008000u;
}
__device__ __forceinline__ u32 dec2(u32 e) {
    u32 s = ((~e) >> 15) & 0x00010001u;
    return e ^ (s * 0x7FFFu) ^ 0x80008000u;
}
__device__ __forceinline__ u32 max2(u32 a, u32 b) {      // per-u16 unsigned max
#if __has_builtin(__builtin_elementwise_max)
    us2 x, y; __builtin_memcpy(&x, &a, 4); __builtin_memcpy(&y, &b, 4);
    us2 r = __builtin_elementwise_max(x, y);
    u32 o; __builtin_memcpy(&o, &r, 4); return o;
#else
    u32 lo = ((a & 0xFFFFu) > (b & 0xFFFFu)) ? (a & 0xFFFFu) : (b & 0xFFFFu);
    u32 hi = ((a >> 16) > (b >> 16)) ? (a & 0xFFFF0000u) : (b & 0xFFFF0000u);
    return lo | hi;
#endif
}

__device__ __forceinline__ u32 spread3(u32 v) {   // 7-bit -> bits {0,3,..,18}
    v &= 0x3FF;
    v = (v | (v << 16)) & 0x030000FF;
    v = (v | (v << 8))  & 0x0300F00F;
    v = (v | (v << 4))  & 0x030C30C3;
    v = (v | (v << 2))  & 0x09249249;
    return v;
}

// ---------------------------------------------------------------------------
// Spatial sort: per cloud, Morton-order the 2048 points (exact R8 kernel,
// verified correct). perm[s] = orig local idx at sorted pos s; iperm[orig]
// = sorted pos. Pure storage permutation.
// ---------------------------------------------------------------------------
__global__ __launch_bounds__(256) void sort_kernel(const float* __restrict__ x,
                                                   u16* __restrict__ perm,
                                                   u16* __restrict__ iperm) {
    __shared__ u32 keys[PCLD];      // 8 KB
    __shared__ float red[256];
    const int cloud = blockIdx.x;
    const int tid = threadIdx.x;
    const float* xc = x + (u64)cloud * PCLD * 3;

    float mn[3] = {1e30f, 1e30f, 1e30f}, mx[3] = {-1e30f, -1e30f, -1e30f};
    for (int m = 0; m < 8; ++m) {
        int t = tid + 256 * m;
        float a = xc[3 * t], b = xc[3 * t + 1], c = xc[3 * t + 2];
        mn[0] = fminf(mn[0], a); mx[0] = fmaxf(mx[0], a);
        mn[1] = fminf(mn[1], b); mx[1] = fmaxf(mx[1], b);
        mn[2] = fminf(mn[2], c); mx[2] = fmaxf(mx[2], c);
    }
    float bmn[3], sc[3];
    for (int d = 0; d < 3; ++d) {
        red[tid] = mn[d]; __syncthreads();
        for (int s = 128; s > 0; s >>= 1) { if (tid < s) red[tid] = fminf(red[tid], red[tid + s]); __syncthreads(); }
        bmn[d] = red[0]; __syncthreads();
        red[tid] = mx[d]; __syncthreads();
        for (int s = 128; s > 0; s >>= 1) { if (tid < s) red[tid] = fmaxf(red[tid], red[tid + s]); __syncthreads(); }
        float rng = red[0] - bmn[d];
        sc[d] = 127.0f / fmaxf(rng, 1e-6f);
        __syncthreads();
    }

    for (int m = 0; m < 8; ++m) {
        int t = tid + 256 * m;
        float a = xc[3 * t], b = xc[3 * t + 1], c = xc[3 * t + 2];
        u32 qa = (u32)fminf(fmaxf((a - bmn[0]) * sc[0], 0.0f), 127.0f);
        u32 qb = (u32)fminf(fmaxf((b - bmn[1]) * sc[1], 0.0f), 127.0f);
        u32 qc = (u32)fminf(fmaxf((c - bmn[2]) * sc[2], 0.0f), 127.0f);
        u32 mort = spread3(qa) | (spread3(qb) << 1) | (spread3(qc) << 2);  // 21 bits
        keys[t] = (mort << 11) | (u32)t;
    }
    __syncthreads();

    for (int k = 2; k <= PCLD; k <<= 1) {
        for (int j = k >> 1; j > 0; j >>= 1) {
            for (int m = 0; m < 4; ++m) {
                int i = tid + 256 * m;                       // 0..1023
                int idx = ((i & ~(j - 1)) << 1) | (i & (j - 1));
                int l = idx | j;
                bool asc = ((idx & k) == 0);
                u32 a = keys[idx], b = keys[l];
                bool sw = asc ? (a > b) : (a < b);
                if (sw) { keys[idx] = b; keys[l] = a; }
            }
            __syncthreads();
        }
    }

    for (int m = 0; m < 8; ++m) {
        int s = tid + 256 * m;
        u16 o = (u16)(keys[s] & 0x7FF);
        perm[cloud * PCLD + s] = o;
        iperm[cloud * PCLD + o] = (u16)s;
    }
}

// ---------------------------------------------------------------------------
// nbr remap: nbrS[s][k] = iperm[ nbr[perm[s]][k] ] — one-shot translation
// of the neighbor table into sorted space. Keeps knn byte-identical.
// ---------------------------------------------------------------------------
__global__ __launch_bounds__(256) void remap_kernel(const u16* __restrict__ nbr,
                                                    const u16* __restrict__ perm,
                                                    const u16* __restrict__ iperm,
                                                    u16* __restrict__ nbrS) {
    const int s = blockIdx.x * 256 + threadIdx.x;   // global sorted row
    const int cl = s >> 11;
    const int base = cl * PCLD;
    const int orig = perm[s];                       // local orig idx
    const u64* src = (const u64*)(nbr + (u64)(base + orig) * KNN);
    const u16* __restrict__ ip = iperm + base;
    u64 nq[5];
#pragma unroll
    for (int w = 0; w < 5; ++w) nq[w] = src[w];
    u16 out[KNN];
#pragma unroll
    for (int t = 0; t < KNN; ++t)
        out[t] = ip[(int)(nq[t >> 2] >> ((t & 3) * 16)) & (PCLD - 1)];
    u64* dst = (u64*)(nbrS + (u64)s * KNN);
#pragma unroll
    for (int w = 0; w < 5; ++w) dst[w] = ((const u64*)out)[w];
}

// ---------------------------------------------------------------------------
// Weight prep: fp32 -> bf16 + transpose (exact R3 version).
// ---------------------------------------------------------------------------
__global__ __launch_bounds__(256) void prep_kernel(
    const float* __restrict__ W1_0, const float* __restrict__ W2_0,
    const float* __restrict__ W1_1, const float* __restrict__ W2_1,
    u16* __restrict__ W1_0T, u16* __restrict__ W2_0T,
    u16* __restrict__ W1_1T, u16* __restrict__ W2_1T) {
    int id = blockIdx.x * 256 + threadIdx.x;   // 4 * 32768 threads
    int m = id >> 15, e = id & 32767;
    if (m == 0)      { int n = e >> 7, k = e & 127; W1_0T[e] = f2bf(W1_0[k * 256 + n]); }
    else if (m == 1) { int n = e >> 8, k = e & 255; W2_0T[e] = f2bf(W2_0[k * 128 + n]); }
    else if (m == 2) { int n = e >> 7, k = e & 127; W1_1T[e] = f2bf(W1_1[k * 256 + n]); }
    else             { int n = e >> 8, k = e & 255; W2_1T[e] = f2bf(W2_1[k * 128 + n]); }
}

// ---------------------------------------------------------------------------
// kNN — EXACT R2 structure (empirical best: 155-164 us; PERMANENTLY FROZEN,
// byte-identical, original space, coalesced output). Failed attacks: R10
// split (214), R12 shared-thr (188), R14 scalar loads (237), R8 sorted
// epilogue (188: scattered writes + iperm gathers inside knn cost 32 us).
// ---------------------------------------------------------------------------
__global__ __launch_bounds__(256) void knn_kernel(const float* __restrict__ x,
                                                  u16* __restrict__ nbr) {
    __shared__ float4 pts[PCLD];
    const int cloud = blockIdx.x >> 3;
    const int qi = ((blockIdx.x & 7) << 8) + threadIdx.x;   // local query idx
    const float* xc = x + (u64)cloud * PCLD * 3;
    for (int t = threadIdx.x; t < PCLD; t += 256) {
        float a = xc[3 * t], b = xc[3 * t + 1], c = xc[3 * t + 2];
        float sq = __fadd_rn(__fadd_rn(__fmul_rn(a, a), __fmul_rn(b, b)), __fmul_rn(c, c));
        pts[t] = make_float4(a, b, c, sq);
    }
    __syncthreads();
    const float4 q = pts[qi];
    const float qx = q.x, qy = q.y, qz = q.z, qs = q.w;
    const int lane = threadIdx.x & 63;
    u64 list[KNN];
#pragma unroll
    for (int k = 0; k < KNN; ++k) list[k] = 0xFF800000FFFFFFFFull;  // enc(+inf)
    float thr = __builtin_inff();

    for (int base = 0; base < PCLD; base += 64) {
        float4 cp = pts[base + lane];   // 1 ds_read_b128 per 64 candidates
        u64 mask = 0;
#pragma unroll
        for (int c = 0; c < 64; ++c) {
            float cx = __uint_as_float(__builtin_amdgcn_readlane(__float_as_uint(cp.x), c));
            float cy = __uint_as_float(__builtin_amdgcn_readlane(__float_as_uint(cp.y), c));
            float cz = __uint_as_float(__builtin_amdgcn_readlane(__float_as_uint(cp.z), c));
            float cs = __uint_as_float(__builtin_amdgcn_readlane(__float_as_uint(cp.w), c));
            float dot = __builtin_fmaf(cz, qz, __builtin_fmaf(cy, qy, __fmul_rn(cx, qx)));
            float d = __fsub_rn(__fadd_rn(qs, cs), __fmul_rn(2.0f, dot));
            if (d < thr) mask |= (1ull << c);
        }
        while (mask) {
            int c = __builtin_ctzll(mask);
            mask &= mask - 1;
            float4 p2 = pts[base + c];
            float dot = __builtin_fmaf(p2.z, qz, __builtin_fmaf(p2.y, qy, __fmul_rn(p2.x, qx)));
            float d = __fsub_rn(__fadd_rn(qs, p2.w), __fmul_rn(2.0f, dot));
            if (d < thr) {
                u32 ub = __float_as_uint(d);
                u32 e = (ub & 0x80000000u) ? ~ub : (ub | 0x80000000u);
                u64 key = (((u64)e) << 32) | (u32)(base + c);
#pragma unroll
                for (int k = 0; k < KNN; ++k) {
                    u64 lo = key < list[k] ? key : list[k];
                    u64 hi = key < list[k] ? list[k] : key;
                    list[k] = lo; key = hi;
                }
                u32 e19 = (u32)(list[KNN - 1] >> 32);
                u32 ud = (e19 & 0x80000000u) ? (e19 & 0x7FFFFFFFu) : ~e19;
                thr = __uint_as_float(ud);
            }
        }
    }
    u16* out = nbr + (u64)(cloud * PCLD + qi) * KNN;
#pragma unroll
    for (int k = 0; k < KNN; ++k) out[k] = (u16)(u32)list[k];
}

// ---------------------------------------------------------------------------
// Transfer MLP: h0 = encode(bf16(x @ Wt + bt)), row-major he[row][128],
// written at the SORTED position (256-B contiguous row, rows scattered).
// ---------------------------------------------------------------------------
__global__ __launch_bounds__(256) void feat_kernel(const float* __restrict__ x,
                                                   const float* __restrict__ Wt,
                                                   const float* __restrict__ bt,
                                                   const u16* __restrict__ iperm,
                                                   u16* __restrict__ h0e) {
    int gid = blockIdx.x * 256 + threadIdx.x;   // NPTS*16
    int i = gid >> 4;
    int g = gid & 15;            // 8-channel group within the row
    int c0 = g << 3;
    float x0 = x[3 * i], x1 = x[3 * i + 1], x2 = x[3 * i + 2];
    u32 o[4];
#pragma unroll
    for (int j = 0; j < 8; j += 2) {
        int c = c0 + j;
        float a0 = bt[c]     + x0 * Wt[c]     + x1 * Wt[128 + c]     + x2 * Wt[256 + c];
        float a1 = bt[c + 1] + x0 * Wt[c + 1] + x1 * Wt[128 + c + 1] + x2 * Wt[256 + c + 1];
        o[j >> 1] = enc2(((u32)f2bf(a0)) | (((u32)f2bf(a1)) << 16));
    }
    const int cl = i >> 11;
    const int ri = cl * PCLD + (int)iperm[i];   // sorted row
    uint4* dst = (uint4*)&h0e[(u64)ri * HD + c0];
    *dst = make_uint4(o[0], o[1], o[2], o[3]);
}

// ---------------------------------------------------------------------------
// Fused GEMM layer — R7 structure (coalesced quarters), SORTED space:
// a 64-row tile is a spatial ball; its neighbor rows concentrate in
// ~100-300 distinct rows (~25-75 KB) -> mostly L1-resident across the
// block's 336 gather instructions (attacks the ~25 us/layer L1-miss cost
// R7 exposed). gemm1 epilogue un-permutes via perm (L1-hot 4 KB/cloud).
// ---------------------------------------------------------------------------
template <int RELU_OUT, int OUT_F32>
__global__ __launch_bounds__(256) void gemm_kernel(
    const u16* __restrict__ he, const u16* __restrict__ nbrS,
    const u16* __restrict__ perm_,
    const u16* __restrict__ W1T, const float* __restrict__ b1,
    const u16* __restrict__ W2T, const float* __restrict__ b2,
    const float* __restrict__ g, const float* __restrict__ be,
    const float* __restrict__ rm, const float* __restrict__ rv,
    void* __restrict__ hout_v) {
    __shared__ u16 aggL[64][136];   // +8 pad (272 B row stride = 17x16 B)
    __shared__ u16 hidL[64][264];   // +8 pad
    const int tid = threadIdx.x;
    // XCD-aware swizzle: 1024 blocks = 32 clouds x 32 tiles; b%8 == XCD id.
    const int b = blockIdx.x;
    const int xcd = b & 7, j = b >> 3;           // j in [0,128)
    const int cloud = xcd + 8 * (j >> 5);        // 4 clouds per XCD
    const int tile = j & 31;
    const int R = cloud * PCLD + tile * 64;      // global sorted row base

    // ---- Phase A: fused neighbor-max gather (L1/L2) + decode -> aggL
    {
        const int r = tid >> 2, cg = tid & 3;    // 64 rows x 4 thr
        const int co = cg * 8;                   // u16 offset of 16-B quarter
        const int grow = R + r;
        const u16* __restrict__ hrow = he + (u64)grow * HD;
        uint4 m0 = *(const uint4*)&hrow[co];
        uint4 m1 = *(const uint4*)&hrow[32 + co];
        uint4 m2 = *(const uint4*)&hrow[64 + co];
        uint4 m3 = *(const uint4*)&hrow[96 + co];
        const u64* nb8 = (const u64*)(nbrS + (u64)grow * KNN);
        u64 nq[5];
#pragma unroll
        for (int w = 0; w < 5; ++w) nq[w] = nb8[w];
        const u16* __restrict__ hcl = he + (u64)cloud * PCLD * HD;
#pragma unroll 4
        for (int t = 0; t < KNN; ++t) {
            int loc = (int)(nq[t >> 2] >> ((t & 3) * 16)) & (PCLD - 1);
            const u16* __restrict__ vrow = hcl + (u64)loc * HD;
            uint4 v0 = *(const uint4*)&vrow[co];
            uint4 v1 = *(const uint4*)&vrow[32 + co];
            uint4 v2 = *(const uint4*)&vrow[64 + co];
            uint4 v3 = *(const uint4*)&vrow[96 + co];
            m0.x = max2(m0.x, v0.x); m0.y = max2(m0.y, v0.y);
            m0.z = max2(m0.z, v0.z); m0.w = max2(m0.w, v0.w);
            m1.x = max2(m1.x, v1.x); m1.y = max2(m1.y, v1.y);
            m1.z = max2(m1.z, v1.z); m1.w = max2(m1.w, v1.w);
            m2.x = max2(m2.x, v2.x); m2.y = max2(m2.y, v2.y);
            m2.z = max2(m2.z, v2.z); m2.w = max2(m2.w, v2.w);
            m3.x = max2(m3.x, v3.x); m3.y = max2(m3.y, v3.y);
            m3.z = max2(m3.z, v3.z); m3.w = max2(m3.w, v3.w);
        }
        *(uint4*)&aggL[r][co]      = make_uint4(dec2(m0.x), dec2(m0.y), dec2(m0.z), dec2(m0.w));
        *(uint4*)&aggL[r][32 + co] = make_uint4(dec2(m1.x), dec2(m1.y), dec2(m1.z), dec2(m1.w));
        *(uint4*)&aggL[r][64 + co] = make_uint4(dec2(m2.x), dec2(m2.y), dec2(m2.z), dec2(m2.w));
        *(uint4*)&aggL[r][96 + co] = make_uint4(dec2(m3.x), dec2(m3.y), dec2(m3.z), dec2(m3.w));
    }
    __syncthreads();

    const int wv = tid >> 6, lane = tid & 63;
    const int lr = lane & 15;
    const int lq = lane >> 4;

    // ---- Phase B: hid = relu(agg @ W1 + b1) -> hidL  (wave owns 64 n-cols)
    {
        f32x4 acc[4][4];
#pragma unroll
        for (int i = 0; i < 4; ++i)
#pragma unroll
            for (int j2 = 0; j2 < 4; ++j2) acc[i][j2] = (f32x4)(0.0f);
        const int nb0 = wv * 64;
#pragma unroll
        for (int ks = 0; ks < 4; ++ks) {
            const int kcol = ks * 32 + lq * 8;
            bf16x8 af[4], bfr[4];
#pragma unroll
            for (int mt = 0; mt < 4; ++mt)
                af[mt] = *(const bf16x8*)&aggL[mt * 16 + lr][kcol];
#pragma unroll
            for (int nt = 0; nt < 4; ++nt)
                bfr[nt] = *(const bf16x8*)&W1T[(u64)(nb0 + nt * 16 + lr) * HD + kcol];
#pragma unroll
            for (int mt = 0; mt < 4; ++mt)
#pragma unroll
                for (int nt = 0; nt < 4; ++nt)
                    acc[mt][nt] = __builtin_amdgcn_mfma_f32_16x16x32_bf16(af[mt], bfr[nt], acc[mt][nt], 0, 0, 0);
        }
#pragma unroll
        for (int nt = 0; nt < 4; ++nt) {
            const int c = nb0 + nt * 16 + lr;
            const float bias = b1[c];
#pragma unroll
            for (int mt = 0; mt < 4; ++mt)
#pragma unroll
                for (int r2 = 0; r2 < 4; ++r2) {
                    float v = fmaxf(acc[mt][nt][r2] + bias, 0.0f);
                    hidL[mt * 16 + lq * 4 + r2][c] = f2bf(v);
                }
        }
    }
    __syncthreads();

    // ---- Phase C: out = BN(hid @ W2 + b2) (+ReLU) -> global
    {
        f32x4 acc[4][2];
#pragma unroll
        for (int i = 0; i < 4; ++i) { acc[i][0] = (f32x4)(0.0f); acc[i][1] = (f32x4)(0.0f); }
        const int nb0 = wv * 32;
#pragma unroll
        for (int ks = 0; ks < 8; ++ks) {
            const int kcol = ks * 32 + lq * 8;
            bf16x8 af[4], bfr[2];
#pragma unroll
            for (int mt = 0; mt < 4; ++mt)
                af[mt] = *(const bf16x8*)&hidL[mt * 16 + lr][kcol];
#pragma unroll
            for (int nt = 0; nt < 2; ++nt)
                bfr[nt] = *(const bf16x8*)&W2T[(u64)(nb0 + nt * 16 + lr) * HD2 + kcol];
#pragma unroll
            for (int mt = 0; mt < 4; ++mt)
#pragma unroll
                for (int nt = 0; nt < 2; ++nt)
                    acc[mt][nt] = __builtin_amdgcn_mfma_f32_16x16x32_bf16(af[mt], bfr[nt], acc[mt][nt], 0, 0, 0);
        }
#pragma unroll
        for (int nt = 0; nt < 2; ++nt) {
            const int c = nb0 + nt * 16 + lr;
            const float bias = b2[c];
            const float sc = g[c] * (1.0f / sqrtf(rv[c] + 1e-5f));
            const float rmc = rm[c];
            const float bec = be[c];
#pragma unroll
            for (int mt = 0; mt < 4; ++mt)
#pragma unroll
                for (int r2 = 0; r2 < 4; ++r2) {
                    float v = acc[mt][nt][r2] + bias;
                    v = (v - rmc) * sc + bec;
                    if (RELU_OUT) v = fmaxf(v, 0.0f);
                    const int lrow = tile * 64 + mt * 16 + lq * 4 + r2;   // local sorted
                    if (OUT_F32) {
                        const int orow = cloud * PCLD + (int)perm_[cloud * PCLD + lrow];
                        ((float*)hout_v)[(u64)orow * HD + c] = v;   // un-permute
                    } else {
                        u16 bb = f2bf(v);
                        u16 e = bb ^ ((bb & 0x8000u) ? (u16)0xFFFFu : (u16)0x8000u);
                        ((u16*)hout_v)[(u64)(cloud * PCLD + lrow) * HD + c] = e;  // stay sorted
                    }
                }
        }
    }
}

// ---------------------------------------------------------------------------
extern "C" void kernel_launch(void* const* d_in, const int* in_sizes, int n_in,
                              void* d_out, int out_size, void* d_ws, size_t ws_size,
                              hipStream_t stream) {
    const float* x    = (const float*)d_in[0];
    const float* Wt   = (const float*)d_in[2];
    const float* bt   = (const float*)d_in[3];
    const float* W1_0 = (const float*)d_in[4];
    const float* b1_0 = (const float*)d_in[5];
    const float* W2_0 = (const float*)d_in[6];
    const float* b2_0 = (const float*)d_in[7];
    const float* g0   = (const float*)d_in[8];
    const float* be0  = (const float*)d_in[9];
    const float* rm0  = (const float*)d_in[10];
    const float* rv0  = (const float*)d_in[11];
    const float* W1_1 = (const float*)d_in[12];
    const float* b1_1 = (const float*)d_in[13];
    const float* W2_1 = (const float*)d_in[14];
    const float* b2_1 = (const float*)d_in[15];
    const float* g1   = (const float*)d_in[16];
    const float* be1  = (const float*)d_in[17];
    const float* rm1  = (const float*)d_in[18];
    const float* rv1  = (const float*)d_in[19];

    char* ws = (char*)d_ws;
    u16* he0  = (u16*)ws;                                   // 16 MB layer-0 acts (sorted)
    u16* he1  = (u16*)(ws + 16777216);                      // 16 MB layer-1 acts (sorted)
    u16* W10T = (u16*)(ws + 2 * 16777216);                  // 64 KB each
    u16* W20T = W10T + 32768;
    u16* W11T = W20T + 32768;
    u16* W21T = W11T + 32768;
    u16* nbr  = (u16*)(ws + 2 * 16777216 + 4 * 65536);      // 2.62 MB (orig space)
    u16* nbrS = nbr + (u64)NPTS * KNN;                      // 2.62 MB (sorted space)
    u16* perm = nbrS + (u64)NPTS * KNN;                     // 128 KB
    u16* iperm = perm + NPTS;                               // 128 KB
    // total ws ~39.4 MB

    knn_kernel<<<256, 256, 0, stream>>>(x, nbr);            // frozen, orig space
    sort_kernel<<<32, 256, 0, stream>>>(x, perm, iperm);
    remap_kernel<<<256, 256, 0, stream>>>(nbr, perm, iperm, nbrS);
    prep_kernel<<<512, 256, 0, stream>>>(W1_0, W2_0, W1_1, W2_1, W10T, W20T, W11T, W21T);
    feat_kernel<<<4096, 256, 0, stream>>>(x, Wt, bt, iperm, he0);
    // layer 0: fused gather+GEMM in sorted space, he0 -> he1
    gemm_kernel<1, 0><<<1024, 256, 0, stream>>>(he0, nbrS, perm, W10T, b1_0, W20T, b2_0,
                                                g0, be0, rm0, rv0, he1);
    // layer 1: fused gather+GEMM, he1 -> d_out (fp32, un-permuted)
    gemm_kernel<0, 1><<<1024, 256, 0, stream>>>(he1, nbrS, perm, W11T, b1_1, W21T, b2_1,
                                                g1, be1, rm1, rv1, d_out);
}

// Round 10
// 325.491 us; speedup vs baseline: 1.1900x; 1.1064x over previous
//
#include <hip/hip_runtime.h>

typedef unsigned int u32;
typedef unsigned short u16;
typedef unsigned long long u64;

// Problem constants
#define NPTS 65536
#define PCLD 2048
#define KNN 20
#define HD 128
#define HD2 256
// activations at rest: ROW-MAJOR order-encoded u16: he[row][128] (256 B/row).
// Row-major lets the fused gather read full 256 B neighbor rows from L2.

typedef __attribute__((ext_vector_type(8))) short bf16x8;   // 8 bf16 (4 VGPRs)
typedef __attribute__((ext_vector_type(4))) float f32x4;    // C/D frag
typedef unsigned short us2 __attribute__((ext_vector_type(2)));

__device__ __forceinline__ u16 f2bf(float f) {
    u32 u = __float_as_uint(f);
    u32 r = (u + 0x7FFFu + ((u >> 16) & 1u)) >> 16;  // RNE
    return (u16)r;
}
// order-encode: bf16 bits -> monotone u16 (unsigned compare == float compare)
__device__ __forceinline__ u32 enc2(u32 b) {             // 2 packed values
    u32 s = (b >> 15) & 0x00010001u;
    return b ^ (s * 0x7FFFu) ^ 0x80008000u;
}
__device__ __forceinline__ u32 dec2(u32 e) {
    u32 s = ((~e) >> 15) & 0x00010001u;
    return e ^ (s * 0x7FFFu) ^ 0x80008000u;
}
__device__ __forceinline__ u32 max2(u32 a, u32 b) {      // per-u16 unsigned max
#if __has_builtin(__builtin_elementwise_max)
    us2 x, y; __builtin_memcpy(&x, &a, 4); __builtin_memcpy(&y, &b, 4);
    us2 r = __builtin_elementwise_max(x, y);
    u32 o; __builtin_memcpy(&o, &r, 4); return o;
#else
    u32 lo = ((a & 0xFFFFu) > (b & 0xFFFFu)) ? (a & 0xFFFFu) : (b & 0xFFFFu);
    u32 hi = ((a >> 16) > (b >> 16)) ? (a & 0xFFFF0000u) : (b & 0xFFFF0000u);
    return lo | hi;
#endif
}

// ---------------------------------------------------------------------------
// Weight prep: fp32 -> bf16 + transpose (exact R3 version).
// ---------------------------------------------------------------------------
__global__ __launch_bounds__(256) void prep_kernel(
    const float* __restrict__ W1_0, const float* __restrict__ W2_0,
    const float* __restrict__ W1_1, const float* __restrict__ W2_1,
    u16* __restrict__ W1_0T, u16* __restrict__ W2_0T,
    u16* __restrict__ W1_1T, u16* __restrict__ W2_1T) {
    int id = blockIdx.x * 256 + threadIdx.x;   // 4 * 32768 threads
    int m = id >> 15, e = id & 32767;
    if (m == 0)      { int n = e >> 7, k = e & 127; W1_0T[e] = f2bf(W1_0[k * 256 + n]); }
    else if (m == 1) { int n = e >> 8, k = e & 255; W2_0T[e] = f2bf(W2_0[k * 128 + n]); }
    else if (m == 2) { int n = e >> 7, k = e & 127; W1_1T[e] = f2bf(W1_1[k * 256 + n]); }
    else             { int n = e >> 8, k = e & 255; W2_1T[e] = f2bf(W2_1[k * 128 + n]); }
}

// ---------------------------------------------------------------------------
// kNN — EXACT R2 structure (empirical best: 155-164 us; PERMANENTLY FROZEN).
// Failed attacks: R10 candidate-split (214, insertion inflation); R12
// shared-thr split (188, split machinery > latency gain); R14 scalar
// candidate loads (237, SMEM-latency-bound); R8 sorted epilogue (188,
// scattered writes + iperm gathers). Single-wave VALU-latency floor.
// ---------------------------------------------------------------------------
__global__ __launch_bounds__(256) void knn_kernel(const float* __restrict__ x,
                                                  u16* __restrict__ nbr) {
    __shared__ float4 pts[PCLD];
    const int cloud = blockIdx.x >> 3;
    const int qi = ((blockIdx.x & 7) << 8) + threadIdx.x;   // local query idx
    const float* xc = x + (u64)cloud * PCLD * 3;
    for (int t = threadIdx.x; t < PCLD; t += 256) {
        float a = xc[3 * t], b = xc[3 * t + 1], c = xc[3 * t + 2];
        float sq = __fadd_rn(__fadd_rn(__fmul_rn(a, a), __fmul_rn(b, b)), __fmul_rn(c, c));
        pts[t] = make_float4(a, b, c, sq);
    }
    __syncthreads();
    const float4 q = pts[qi];
    const float qx = q.x, qy = q.y, qz = q.z, qs = q.w;
    const int lane = threadIdx.x & 63;
    u64 list[KNN];
#pragma unroll
    for (int k = 0; k < KNN; ++k) list[k] = 0xFF800000FFFFFFFFull;  // enc(+inf)
    float thr = __builtin_inff();

    for (int base = 0; base < PCLD; base += 64) {
        float4 cp = pts[base + lane];   // 1 ds_read_b128 per 64 candidates
        u64 mask = 0;
#pragma unroll
        for (int c = 0; c < 64; ++c) {
            float cx = __uint_as_float(__builtin_amdgcn_readlane(__float_as_uint(cp.x), c));
            float cy = __uint_as_float(__builtin_amdgcn_readlane(__float_as_uint(cp.y), c));
            float cz = __uint_as_float(__builtin_amdgcn_readlane(__float_as_uint(cp.z), c));
            float cs = __uint_as_float(__builtin_amdgcn_readlane(__float_as_uint(cp.w), c));
            float dot = __builtin_fmaf(cz, qz, __builtin_fmaf(cy, qy, __fmul_rn(cx, qx)));
            float d = __fsub_rn(__fadd_rn(qs, cs), __fmul_rn(2.0f, dot));
            if (d < thr) mask |= (1ull << c);
        }
        while (mask) {
            int c = __builtin_ctzll(mask);
            mask &= mask - 1;
            float4 p2 = pts[base + c];
            float dot = __builtin_fmaf(p2.z, qz, __builtin_fmaf(p2.y, qy, __fmul_rn(p2.x, qx)));
            float d = __fsub_rn(__fadd_rn(qs, p2.w), __fmul_rn(2.0f, dot));
            if (d < thr) {
                u32 ub = __float_as_uint(d);
                u32 e = (ub & 0x80000000u) ? ~ub : (ub | 0x80000000u);
                u64 key = (((u64)e) << 32) | (u32)(base + c);
#pragma unroll
                for (int k = 0; k < KNN; ++k) {
                    u64 lo = key < list[k] ? key : list[k];
                    u64 hi = key < list[k] ? list[k] : key;
                    list[k] = lo; key = hi;
                }
                u32 e19 = (u32)(list[KNN - 1] >> 32);
                u32 ud = (e19 & 0x80000000u) ? (e19 & 0x7FFFFFFFu) : ~e19;
                thr = __uint_as_float(ud);
            }
        }
    }
    u16* out = nbr + (u64)(cloud * PCLD + qi) * KNN;
#pragma unroll
    for (int k = 0; k < KNN; ++k) out[k] = (u16)(u32)list[k];
}

// ---------------------------------------------------------------------------
// Transfer MLP: h0 = encode(bf16(x @ Wt + bt)), ROW-MAJOR he[row][128].
// Consecutive threads cover one row's 256 B -> coalesced uint4 stores.
// ---------------------------------------------------------------------------
__global__ __launch_bounds__(256) void feat_kernel(const float* __restrict__ x,
                                                   const float* __restrict__ Wt,
                                                   const float* __restrict__ bt,
                                                   u16* __restrict__ h0e) {
    int gid = blockIdx.x * 256 + threadIdx.x;   // NPTS*16
    int i = gid >> 4;
    int g = gid & 15;            // 8-channel group within the row
    int c0 = g << 3;
    float x0 = x[3 * i], x1 = x[3 * i + 1], x2 = x[3 * i + 2];
    u32 o[4];
#pragma unroll
    for (int j = 0; j < 8; j += 2) {
        int c = c0 + j;
        float a0 = bt[c]     + x0 * Wt[c]     + x1 * Wt[128 + c]     + x2 * Wt[256 + c];
        float a1 = bt[c + 1] + x0 * Wt[c + 1] + x1 * Wt[128 + c + 1] + x2 * Wt[256 + c + 1];
        o[j >> 1] = enc2(((u32)f2bf(a0)) | (((u32)f2bf(a1)) << 16));
    }
    uint4* dst = (uint4*)&h0e[(u64)i * HD + c0];
    *dst = make_uint4(o[0], o[1], o[2], o[3]);
}

// ---------------------------------------------------------------------------
// Fused GEMM layer — R7 structure (VERIFIED BEST: 322.5 total).
// Phase A gathers own+20 neighbor rows from row-major he via L2 with the
// coalesced-quarter mapping: thread cg reads the cg-th 16-B quarter of each
// 64-B segment ({0,64,128,192}+cg*16) -> 4 cg-lanes per row coalesce into
// one segment -> 16 L1 lookups/instr (4x fewer than chunk-contiguous; R7
// win −18 us). Gather volume itself is a random-access throughput floor:
// LDS-staged (R0), L2-gather (R3), retile (R5), Morton-sorted (R9) all
// land at ~40-45 us/layer. Phases B/C: 16x16x32 bf16 MFMA, unchanged.
// ---------------------------------------------------------------------------
template <int RELU_OUT, int OUT_F32>
__global__ __launch_bounds__(256) void gemm_kernel(
    const u16* __restrict__ he, const u16* __restrict__ nbr_,
    const u16* __restrict__ W1T, const float* __restrict__ b1,
    const u16* __restrict__ W2T, const float* __restrict__ b2,
    const float* __restrict__ g, const float* __restrict__ be,
    const float* __restrict__ rm, const float* __restrict__ rv,
    void* __restrict__ hout_v) {
    __shared__ u16 aggL[64][136];   // +8 pad (272 B row stride = 17x16 B, aligned)
    __shared__ u16 hidL[64][264];   // +8 pad
    const int tid = threadIdx.x;
    // XCD-aware swizzle: 1024 blocks = 32 clouds x 32 tiles; b%8 == XCD id.
    const int b = blockIdx.x;
    const int xcd = b & 7, j = b >> 3;           // j in [0,128)
    const int cloud = xcd + 8 * (j >> 5);        // 4 clouds per XCD
    const int tile = j & 31;
    const int R = cloud * PCLD + tile * 64;      // global row base

    // ---- Phase A: fused neighbor-max gather (L2) + decode -> aggL
    {
        const int r = tid >> 2, cg = tid & 3;    // 64 rows x 4 thr
        const int co = cg * 8;                   // u16 offset of this thread's 16-B quarter
        const int grow = R + r;
        const u16* __restrict__ hrow = he + (u64)grow * HD;
        uint4 m0 = *(const uint4*)&hrow[co];
        uint4 m1 = *(const uint4*)&hrow[32 + co];
        uint4 m2 = *(const uint4*)&hrow[64 + co];
        uint4 m3 = *(const uint4*)&hrow[96 + co];
        const u64* nb8 = (const u64*)(nbr_ + (u64)grow * KNN);
        u64 nq[5];
#pragma unroll
        for (int w = 0; w < 5; ++w) nq[w] = nb8[w];
        const u16* __restrict__ hcl = he + (u64)cloud * PCLD * HD;
#pragma unroll 4
        for (int t = 0; t < KNN; ++t) {
            int loc = (int)(nq[t >> 2] >> ((t & 3) * 16)) & (PCLD - 1);
            const u16* __restrict__ vrow = hcl + (u64)loc * HD;
            uint4 v0 = *(const uint4*)&vrow[co];
            uint4 v1 = *(const uint4*)&vrow[32 + co];
            uint4 v2 = *(const uint4*)&vrow[64 + co];
            uint4 v3 = *(const uint4*)&vrow[96 + co];
            m0.x = max2(m0.x, v0.x); m0.y = max2(m0.y, v0.y);
            m0.z = max2(m0.z, v0.z); m0.w = max2(m0.w, v0.w);
            m1.x = max2(m1.x, v1.x); m1.y = max2(m1.y, v1.y);
            m1.z = max2(m1.z, v1.z); m1.w = max2(m1.w, v1.w);
            m2.x = max2(m2.x, v2.x); m2.y = max2(m2.y, v2.y);
            m2.z = max2(m2.z, v2.z); m2.w = max2(m2.w, v2.w);
            m3.x = max2(m3.x, v3.x); m3.y = max2(m3.y, v3.y);
            m3.z = max2(m3.z, v3.z); m3.w = max2(m3.w, v3.w);
        }
        *(uint4*)&aggL[r][co]      = make_uint4(dec2(m0.x), dec2(m0.y), dec2(m0.z), dec2(m0.w));
        *(uint4*)&aggL[r][32 + co] = make_uint4(dec2(m1.x), dec2(m1.y), dec2(m1.z), dec2(m1.w));
        *(uint4*)&aggL[r][64 + co] = make_uint4(dec2(m2.x), dec2(m2.y), dec2(m2.z), dec2(m2.w));
        *(uint4*)&aggL[r][96 + co] = make_uint4(dec2(m3.x), dec2(m3.y), dec2(m3.z), dec2(m3.w));
    }
    __syncthreads();

    const int wv = tid >> 6, lane = tid & 63;
    const int lr = lane & 15;
    const int lq = lane >> 4;

    // ---- Phase B: hid = relu(agg @ W1 + b1) -> hidL  (wave owns 64 n-cols)
    {
        f32x4 acc[4][4];
#pragma unroll
        for (int i = 0; i < 4; ++i)
#pragma unroll
            for (int j2 = 0; j2 < 4; ++j2) acc[i][j2] = (f32x4)(0.0f);
        const int nb0 = wv * 64;
#pragma unroll
        for (int ks = 0; ks < 4; ++ks) {
            const int kcol = ks * 32 + lq * 8;
            bf16x8 af[4], bfr[4];
#pragma unroll
            for (int mt = 0; mt < 4; ++mt)
                af[mt] = *(const bf16x8*)&aggL[mt * 16 + lr][kcol];
#pragma unroll
            for (int nt = 0; nt < 4; ++nt)
                bfr[nt] = *(const bf16x8*)&W1T[(u64)(nb0 + nt * 16 + lr) * HD + kcol];
#pragma unroll
            for (int mt = 0; mt < 4; ++mt)
#pragma unroll
                for (int nt = 0; nt < 4; ++nt)
                    acc[mt][nt] = __builtin_amdgcn_mfma_f32_16x16x32_bf16(af[mt], bfr[nt], acc[mt][nt], 0, 0, 0);
        }
#pragma unroll
        for (int nt = 0; nt < 4; ++nt) {
            const int c = nb0 + nt * 16 + lr;
            const float bias = b1[c];
#pragma unroll
            for (int mt = 0; mt < 4; ++mt)
#pragma unroll
                for (int r2 = 0; r2 < 4; ++r2) {
                    float v = fmaxf(acc[mt][nt][r2] + bias, 0.0f);
                    hidL[mt * 16 + lq * 4 + r2][c] = f2bf(v);
                }
        }
    }
    __syncthreads();

    // ---- Phase C: out = BN(hid @ W2 + b2) (+ReLU) -> global
    {
        f32x4 acc[4][2];
#pragma unroll
        for (int i = 0; i < 4; ++i) { acc[i][0] = (f32x4)(0.0f); acc[i][1] = (f32x4)(0.0f); }
        const int nb0 = wv * 32;
#pragma unroll
        for (int ks = 0; ks < 8; ++ks) {
            const int kcol = ks * 32 + lq * 8;
            bf16x8 af[4], bfr[2];
#pragma unroll
            for (int mt = 0; mt < 4; ++mt)
                af[mt] = *(const bf16x8*)&hidL[mt * 16 + lr][kcol];
#pragma unroll
            for (int nt = 0; nt < 2; ++nt)
                bfr[nt] = *(const bf16x8*)&W2T[(u64)(nb0 + nt * 16 + lr) * HD2 + kcol];
#pragma unroll
            for (int mt = 0; mt < 4; ++mt)
#pragma unroll
                for (int nt = 0; nt < 2; ++nt)
                    acc[mt][nt] = __builtin_amdgcn_mfma_f32_16x16x32_bf16(af[mt], bfr[nt], acc[mt][nt], 0, 0, 0);
        }
#pragma unroll
        for (int nt = 0; nt < 2; ++nt) {
            const int c = nb0 + nt * 16 + lr;
            const float bias = b2[c];
            const float sc = g[c] * (1.0f / sqrtf(rv[c] + 1e-5f));
            const float rmc = rm[c];
            const float bec = be[c];
#pragma unroll
            for (int mt = 0; mt < 4; ++mt)
#pragma unroll
                for (int r2 = 0; r2 < 4; ++r2) {
                    float v = acc[mt][nt][r2] + bias;
                    v = (v - rmc) * sc + bec;
                    if (RELU_OUT) v = fmaxf(v, 0.0f);
                    const int row = R + mt * 16 + lq * 4 + r2;
                    if (OUT_F32) {
                        ((float*)hout_v)[(u64)row * HD + c] = v;
                    } else {
                        u16 bb = f2bf(v);
                        u16 e = bb ^ ((bb & 0x8000u) ? (u16)0xFFFFu : (u16)0x8000u);
                        ((u16*)hout_v)[(u64)row * HD + c] = e;   // row-major encoded
                    }
                }
        }
    }
}

// ---------------------------------------------------------------------------
extern "C" void kernel_launch(void* const* d_in, const int* in_sizes, int n_in,
                              void* d_out, int out_size, void* d_ws, size_t ws_size,
                              hipStream_t stream) {
    const float* x    = (const float*)d_in[0];
    const float* Wt   = (const float*)d_in[2];
    const float* bt   = (const float*)d_in[3];
    const float* W1_0 = (const float*)d_in[4];
    const float* b1_0 = (const float*)d_in[5];
    const float* W2_0 = (const float*)d_in[6];
    const float* b2_0 = (const float*)d_in[7];
    const float* g0   = (const float*)d_in[8];
    const float* be0  = (const float*)d_in[9];
    const float* rm0  = (const float*)d_in[10];
    const float* rv0  = (const float*)d_in[11];
    const float* W1_1 = (const float*)d_in[12];
    const float* b1_1 = (const float*)d_in[13];
    const float* W2_1 = (const float*)d_in[14];
    const float* b2_1 = (const float*)d_in[15];
    const float* g1   = (const float*)d_in[16];
    const float* be1  = (const float*)d_in[17];
    const float* rm1  = (const float*)d_in[18];
    const float* rv1  = (const float*)d_in[19];

    char* ws = (char*)d_ws;
    u16* he0  = (u16*)ws;                                   // 16 MB layer-0 acts
    u16* he1  = (u16*)(ws + 16777216);                      // 16 MB layer-1 acts
    u16* W10T = (u16*)(ws + 2 * 16777216);                  // 64 KB each
    u16* W20T = W10T + 32768;
    u16* W11T = W20T + 32768;
    u16* W21T = W11T + 32768;
    u16* nbr  = (u16*)(ws + 2 * 16777216 + 4 * 65536);      // 2.62 MB
    // total ws ~35.2 MB

    knn_kernel<<<256, 256, 0, stream>>>(x, nbr);
    prep_kernel<<<512, 256, 0, stream>>>(W1_0, W2_0, W1_1, W2_1, W10T, W20T, W11T, W21T);
    feat_kernel<<<4096, 256, 0, stream>>>(x, Wt, bt, he0);
    // layer 0: fused gather+GEMM, he0 -> he1
    gemm_kernel<1, 0><<<1024, 256, 0, stream>>>(he0, nbr, W10T, b1_0, W20T, b2_0,
                                                g0, be0, rm0, rv0, he1);
    // layer 1: fused gather+GEMM, he1 -> d_out (fp32)
    gemm_kernel<0, 1><<<1024, 256, 0, stream>>>(he1, nbr, W11T, b1_1, W21T, b2_1,
                                                g1, be1, rm1, rv1, d_out);
}